// Round 10
// baseline (539.437 us; speedup 1.0000x reference)
//
#include <hip/hip_runtime.h>
#include <hip/hip_bf16.h>
#include <math.h>

// AdditiveAttention: B=4, Q=512, K=512, H=256, fp32.
// scores[b,q,k] = sum_h wv_h * tanh(qp + kp) -> softmax_k -> @V
// tanh(x) = 1 - 2/(1+e^{2x}); sum_h wv_h drops out of softmax.
// e^{2(q+k)} = e^{2q} * e^{2k}: exponentiate projections once (proj kernel).
// 4 h-terms share one rcp: sum wv_i/t_i = num/(t0*t1*t2*t3).
//
// R4: grid-barrier fusion => cross-XCD coherence storm. Two launches.
// R6/R8: register prefetch pipelines under the VGPR cap => scratch spill.
// R9: LDS-staged ke via global_load_lds works (no spill) BUT (a) read map
//     had 4-8 way bank conflicts (6.29M), (b) phase 3 re-read V 4x (1GB L2).
// R10: conflict-free wave-uniform-hq map + transposed attn matrix so each
//      V float4 is loaded once per block and shared by all 4 q rows.

#define B_ 4
#define Q_ 512
#define K_ 512
#define H_ 256
#define QE_ELEMS (B_ * Q_ * H_)           // 524288
#define KE_ELEMS (B_ * H_ * K_)           // 524288

static constexpr float CEXP = 2.8853900817779268f; // 2*log2(e)
static constexpr float LOG2E = 1.4426950408889634f;

__device__ __forceinline__ float2 pk_fma(float2 a, float2 b, float2 c) {
    return make_float2(fmaf(a.x, b.x, c.x), fmaf(a.y, b.y, c.y));
}
__device__ __forceinline__ float2 pk_mul(float2 a, float2 b) {
    return make_float2(a.x * b.x, a.y * b.y);
}
__device__ __forceinline__ float2 bc2(float s) { return make_float2(s, s); }

// async global->LDS, 16B per lane (global_load_lds_dwordx4)
__device__ __forceinline__ void gl_lds16(const float* g, float* l) {
    __builtin_amdgcn_global_load_lds(
        (const __attribute__((address_space(1))) void*)g,
        (__attribute__((address_space(3))) void*)l, 16, 0, 0);
}

// ---------------------------------------------------------------------------
// proj_exp: 256 blocks x 1024 thr. Block = one 64x64 output tile; 4 teams of
// 256 thr each reduce a 64-d quarter (double-buffered LDS, reg prefetch);
// LDS combine -> exp2 -> store.  blocks [0,128): qe; [128,256): ke[b][h][k].
// ---------------------------------------------------------------------------
#define PJ_AS(team, buf, dd, row) smem[(((team)*2 + (buf)) * 16 + (dd)) * 68 + (row)]
#define PJ_SS(team, buf, dd, row) smem[8704 + (((team)*2 + (buf)) * 16 + (dd)) * 68 + (row)]

__global__ __launch_bounds__(1024, 4) void proj_exp(
    const float* __restrict__ queries, const float* __restrict__ keys,
    const float* __restrict__ Wq, const float* __restrict__ Wk,
    float* __restrict__ qe, float* __restrict__ ke)
{
    __shared__ __align__(16) float smem[17408];   // 69632 B

    const int bid = blockIdx.x;
    const int team = threadIdx.x >> 8;   // d-quarter 0..3 (64 d each)
    const int tid = threadIdx.x & 255;

    const float* A; const float* S; float* C; int ldc;
    if (bid < 128) {                 // qe: [B*Q=2048 x H=256], 32x4 tiles
        int mt = bid >> 2, nt = bid & 3;
        A = queries + (mt * 64) * H_;
        S = Wq + (nt * 64) * H_;
        C = qe + (mt * 64) * H_ + nt * 64;
        ldc = H_;
    } else {                         // ke: per-b [H=256 x K=512], 4x8 tiles
        int id = bid - 128;
        int b = id >> 5, mt = (id >> 3) & 3, nt = id & 7;
        A = Wk + (mt * 64) * H_;
        S = keys + ((long)(b * K_ + nt * 64)) * H_;
        C = ke + ((long)(b * H_ + mt * 64)) * K_ + nt * 64;
        ldc = K_;
    }

    const int tx = tid & 15;         // n0 = tx*4
    const int ty = tid >> 4;         // m0 = ty*4
    const int ldr = tid >> 2;        // staging row 0..63
    const int ldd = (tid & 3) * 4;   // staging d-offset 0,4,8,12
    const float* GA = A + ldr * H_ + team * 64 + ldd;
    const float* GS = S + ldr * H_ + team * 64 + ldd;

    float4 av = *(const float4*)GA;
    float4 sv = *(const float4*)GS;
    PJ_AS(team, 0, ldd + 0, ldr) = av.x; PJ_AS(team, 0, ldd + 1, ldr) = av.y;
    PJ_AS(team, 0, ldd + 2, ldr) = av.z; PJ_AS(team, 0, ldd + 3, ldr) = av.w;
    PJ_SS(team, 0, ldd + 0, ldr) = sv.x; PJ_SS(team, 0, ldd + 1, ldr) = sv.y;
    PJ_SS(team, 0, ldd + 2, ldr) = sv.z; PJ_SS(team, 0, ldd + 3, ldr) = sv.w;

    float acc[4][4] = {};
#pragma unroll
    for (int c = 0; c < 4; ++c) {    // 4 chunks x 16 d = 64 d per team
        const int cur = c & 1;
        if (c < 3) {                 // register prefetch of next chunk
            av = *(const float4*)(GA + (c + 1) * 16);
            sv = *(const float4*)(GS + (c + 1) * 16);
        }
        __syncthreads();             // buf[cur] writes visible
#pragma unroll
        for (int dd = 0; dd < 16; ++dd) {
            float4 a4 = *(const float4*)&PJ_AS(team, cur, dd, ty * 4);
            float4 b4 = *(const float4*)&PJ_SS(team, cur, dd, tx * 4);
            float am[4] = {a4.x, a4.y, a4.z, a4.w};
            float bn[4] = {b4.x, b4.y, b4.z, b4.w};
#pragma unroll
            for (int i = 0; i < 4; ++i)
#pragma unroll
                for (int j = 0; j < 4; ++j)
                    acc[i][j] = fmaf(am[i], bn[j], acc[i][j]);
        }
        if (c < 3) {                 // fill other buffer (last read 2 iters ago)
            const int nxt = cur ^ 1;
            PJ_AS(team, nxt, ldd + 0, ldr) = av.x;
            PJ_AS(team, nxt, ldd + 1, ldr) = av.y;
            PJ_AS(team, nxt, ldd + 2, ldr) = av.z;
            PJ_AS(team, nxt, ldd + 3, ldr) = av.w;
            PJ_SS(team, nxt, ldd + 0, ldr) = sv.x;
            PJ_SS(team, nxt, ldd + 1, ldr) = sv.y;
            PJ_SS(team, nxt, ldd + 2, ldr) = sv.z;
            PJ_SS(team, nxt, ldd + 3, ldr) = sv.w;
        }
    }

    // combine 4 d-quarter partials via LDS (reuse staging), exp, store
    __syncthreads();                 // all staging reads complete
    if (team > 0) {
        float* Cmb = smem + (team - 1) * 4352;   // 64 x 68 tile
#pragma unroll
        for (int i = 0; i < 4; ++i) {
            float4 o = {acc[i][0], acc[i][1], acc[i][2], acc[i][3]};
            *(float4*)&Cmb[(ty * 4 + i) * 68 + tx * 4] = o;
        }
    }
    __syncthreads();
    if (team == 0) {
#pragma unroll
        for (int i = 0; i < 4; ++i) {
            const int off = (ty * 4 + i) * 68 + tx * 4;
            float4 p1 = *(const float4*)&smem[off];
            float4 p2 = *(const float4*)&smem[4352 + off];
            float4 p3 = *(const float4*)&smem[8704 + off];
            float4 o;
            o.x = __builtin_amdgcn_exp2f(CEXP * (acc[i][0] + p1.x + p2.x + p3.x));
            o.y = __builtin_amdgcn_exp2f(CEXP * (acc[i][1] + p1.y + p2.y + p3.y));
            o.z = __builtin_amdgcn_exp2f(CEXP * (acc[i][2] + p1.z + p2.z + p3.z));
            o.w = __builtin_amdgcn_exp2f(CEXP * (acc[i][3] + p1.w + p2.w + p3.w));
            *(float4*)&C[(ty * 4 + i) * ldc + tx * 4] = o;
        }
    }
}

// ---------------------------------------------------------------------------
// attn: 512 blocks x 1024 thr. LDS 78848B -> 2 blocks/CU, VGPR<=64.
// XCD-affine: bid%8 -> XCD; XCD pair {2b,2b+1} serves batch b.
// Phase 1: ke via double-buffered global_load_lds chunks (16h x 512k).
//   Wave w: hq = w&3 (wave-uniform!), kseg = w>>2; lane k2 = kseg*128+lane*2
//   -> all ds_read_b64 contiguous-in-lane (conflict-free). h-partials
//   combined through a kst scratch pass (cross-wave).
// Phase 2: softmax (wave q<4), writes attn TRANSPOSED sT[k][q].
// Phase 3: thread = (h-quad, 32-k segment); each V float4 loaded once,
//   shared by all 4 q (16 fma / 16B); kst reduction over 16 k-segments.
// ---------------------------------------------------------------------------
__global__ __launch_bounds__(1024, 8) void attn(
    const float* __restrict__ qe, const float* __restrict__ ke,
    const float* __restrict__ values, const float* __restrict__ wv,
    float* __restrict__ out)
{
    const int bid = blockIdx.x;
    const int xcd = bid & 7;
    const int b = xcd >> 1;
    const int q0 = (((bid >> 3) << 1) | (xcd & 1)) * 4;
    const int t = threadIdx.x;
    const int lane = t & 63;
    const int w = t >> 6;                 // wave 0..15

    // LDS: kst[2][16*512] | sQ[4*256] | wvs[256] | sS[4*512]  (78848 B)
    __shared__ __align__(16) float smem[2 * 8192 + 1024 + 256 + 2048];
    float* kst = smem;                    // 2 x 8192 (also scratch)
    float* sQ  = smem + 16384;            // [4][H_]
    float* wvs = smem + 17408;            // [H_]
    float* sS  = smem + 17664;            // scores then TRANSPOSED attn [K][4]

    sQ[t] = qe[((long)(b * Q_ + q0 + (t >> 8))) * H_ + (t & 255)];
    if (t < H_) wvs[t] = wv[t];
    // first in-loop barrier covers sQ/wvs visibility

    // ---- Phase 1: scores, LDS-staged ke, conflict-free map
    {
        const float* keB = ke + (long)b * H_ * K_;
        const int sh = t >> 7;            // staging row 0..7
        const int sk = (t & 127) * 4;     // staging col (float4)
        const int hq4 = (w & 3) * 4;      // wave-uniform h-quad base
        const int kseg = w >> 2;          // 0..3
        const int k2 = kseg * 128 + lane * 2;

        gl_lds16(keB + (0 * 16 + sh) * K_ + sk, kst + t * 4);
        gl_lds16(keB + (0 * 16 + 8 + sh) * K_ + sk, kst + 4096 + t * 4);

        float2 acc[4] = {};               // acc[q]: .x k2, .y k2+1
        const float2 one2 = {1.0f, 1.0f};

        for (int c = 0; c < 16; ++c) {
            const int cur = c & 1;
            __syncthreads();              // drains stage(c); chunk c ready
            if (c < 15) {                 // async-fill other buffer NOW
                float* nb = kst + (cur ^ 1) * 8192;
                gl_lds16(keB + ((c + 1) * 16 + sh) * K_ + sk, nb + t * 4);
                gl_lds16(keB + ((c + 1) * 16 + 8 + sh) * K_ + sk,
                         nb + 4096 + t * 4);
            }
            const float* kb = kst + cur * 8192;
            float2 c0 = *(const float2*)&kb[(hq4 + 0) * 512 + k2];
            float2 c1 = *(const float2*)&kb[(hq4 + 1) * 512 + k2];
            float2 c2 = *(const float2*)&kb[(hq4 + 2) * 512 + k2];
            float2 c3 = *(const float2*)&kb[(hq4 + 3) * 512 + k2];
            const int h = c * 16 + hq4;
            float4 w4 = *(const float4*)&wvs[h];
#pragma unroll
            for (int q = 0; q < 4; ++q) {
                float4 e = *(const float4*)&sQ[q * H_ + h];
                float2 t0 = pk_fma(bc2(e.x), c0, one2);
                float2 t1 = pk_fma(bc2(e.y), c1, one2);
                float2 t2 = pk_fma(bc2(e.z), c2, one2);
                float2 t3 = pk_fma(bc2(e.w), c3, one2);
                float2 d01 = pk_mul(t0, t1);
                float2 d23 = pk_mul(t2, t3);
                float2 n01 = pk_fma(bc2(w4.x), t1, pk_mul(bc2(w4.y), t0));
                float2 n23 = pk_fma(bc2(w4.z), t3, pk_mul(bc2(w4.w), t2));
                float2 num = pk_fma(n01, d23, pk_mul(n23, d01));
                float2 den = pk_mul(d01, d23);
                acc[q].x = fmaf(num.x, __builtin_amdgcn_rcpf(den.x), acc[q].x);
                acc[q].y = fmaf(num.y, __builtin_amdgcn_rcpf(den.y), acc[q].y);
            }
        }

        __syncthreads();                  // chunk-15 reads done; kst reusable
        // cross-wave h-combine via scratch: part[(w*4+q)*64+lane] (float2)
#pragma unroll
        for (int q = 0; q < 4; ++q)
            *(float2*)&kst[((w * 4 + q) * 64 + lane) * 2] = acc[q];
        __syncthreads();
        {
            const int ks2 = t >> 8;       // 0..3
            const int q = (t >> 6) & 3;
            float2 s = {0.f, 0.f};
#pragma unroll
            for (int hq = 0; hq < 4; ++hq) {
                float2 p = *(const float2*)
                    &kst[(((ks2 * 4 + hq) * 4 + q) * 64 + lane) * 2];
                s.x += p.x; s.y += p.y;
            }
            float2 o = {-2.0f * s.x, -2.0f * s.y};
            *(float2*)&sS[q * K_ + ks2 * 128 + lane * 2] = o;
        }
    }
    __syncthreads();

    // ---- Phase 2: softmax (wave q<4 -> row q), output TRANSPOSED sT[k][4]
    {
        const int q = w;
        float sv[8];
        float rs = 0.f;
        if (q < 4) {
            float m = -INFINITY;
#pragma unroll
            for (int j = 0; j < 8; ++j) {
                sv[j] = sS[q * K_ + lane + 64 * j];
                m = fmaxf(m, sv[j]);
            }
#pragma unroll
            for (int off = 32; off >= 1; off >>= 1)
                m = fmaxf(m, __shfl_xor(m, off));
            float sum = 0.f;
#pragma unroll
            for (int j = 0; j < 8; ++j) {
                sv[j] = __builtin_amdgcn_exp2f((sv[j] - m) * LOG2E);
                sum += sv[j];
            }
#pragma unroll
            for (int off = 32; off >= 1; off >>= 1) sum += __shfl_xor(sum, off);
            rs = 1.0f / sum;
        }
        __syncthreads();                  // all row-major reads complete
        if (q < 4) {
#pragma unroll
            for (int j = 0; j < 8; ++j)
                sS[(lane + 64 * j) * 4 + q] = sv[j] * rs;   // sT[k][q]
        }
    }
    __syncthreads();

    // ---- Phase 3: attn @ V, V loaded once, shared across 4 q
    {
        const int h4 = lane * 4;
        const int kseg = w;               // 0..15, 32 k each
        const float* vb = values + (long)b * K_ * H_ + h4;
        float4 a0 = {0,0,0,0}, a1 = {0,0,0,0}, a2 = {0,0,0,0}, a3 = {0,0,0,0};
        const int kbeg = kseg * 32;
#pragma unroll 4
        for (int k = kbeg; k < kbeg + 32; ++k) {
            float4 v = *(const float4*)&vb[(long)k * H_];
            float4 a = *(const float4*)&sS[k * 4];   // broadcast (uniform k)
            a0.x = fmaf(a.x, v.x, a0.x); a0.y = fmaf(a.x, v.y, a0.y);
            a0.z = fmaf(a.x, v.z, a0.z); a0.w = fmaf(a.x, v.w, a0.w);
            a1.x = fmaf(a.y, v.x, a1.x); a1.y = fmaf(a.y, v.y, a1.y);
            a1.z = fmaf(a.y, v.z, a1.z); a1.w = fmaf(a.y, v.w, a1.w);
            a2.x = fmaf(a.z, v.x, a2.x); a2.y = fmaf(a.z, v.y, a2.y);
            a2.z = fmaf(a.z, v.z, a2.z); a2.w = fmaf(a.z, v.w, a2.w);
            a3.x = fmaf(a.w, v.x, a3.x); a3.y = fmaf(a.w, v.y, a3.y);
            a3.z = fmaf(a.w, v.z, a3.z); a3.w = fmaf(a.w, v.w, a3.w);
        }
        float4* sRed = (float4*)kst;      // 16 kseg x 4 q x 64 lanes = 64KB
        sRed[(kseg * 4 + 0) * 64 + lane] = a0;
        sRed[(kseg * 4 + 1) * 64 + lane] = a1;
        sRed[(kseg * 4 + 2) * 64 + lane] = a2;
        sRed[(kseg * 4 + 3) * 64 + lane] = a3;
        __syncthreads();
        if (t < 256) {
            const int q = t >> 6;
            float4 s = {0.f, 0.f, 0.f, 0.f};
#pragma unroll
            for (int kk = 0; kk < 16; ++kk) {
                float4 p = sRed[(kk * 4 + q) * 64 + lane];
                s.x += p.x; s.y += p.y; s.z += p.z; s.w += p.w;
            }
            *(float4*)&out[((long)(b * Q_ + q0 + q)) * H_ + lane * 4] = s;
        }
    }
}

extern "C" void kernel_launch(void* const* d_in, const int* in_sizes, int n_in,
                              void* d_out, int out_size, void* d_ws, size_t ws_size,
                              hipStream_t stream) {
    const float* queries = (const float*)d_in[0];  // [B,Q,H]
    const float* keys    = (const float*)d_in[1];  // [B,K,H]
    const float* values  = (const float*)d_in[2];  // [B,K,H]
    const float* Wq      = (const float*)d_in[3];  // [H,H]
    const float* Wk      = (const float*)d_in[4];  // [H,H]
    const float* wv      = (const float*)d_in[5];  // [H]
    float* out = (float*)d_out;

    // ws: [qe 2MB][ke 2MB]
    float* qe = (float*)d_ws;
    float* ke = qe + QE_ELEMS;

    proj_exp<<<256, 1024, 0, stream>>>(queries, keys, Wq, Wk, qe, ke);
    attn<<<512, 1024, 0, stream>>>(qe, ke, values, wv, out);
}

// Round 11
// 531.975 us; speedup vs baseline: 1.0140x; 1.0140x over previous
//
#include <hip/hip_runtime.h>
#include <hip/hip_bf16.h>
#include <math.h>

// AdditiveAttention: B=4, Q=512, K=512, H=256, fp32.
// scores[b,q,k] = sum_h wv_h * tanh(qp + kp) -> softmax_k -> @V
// tanh(x) = 1 - 2/(1+e^{2x}); sum_h wv_h drops out of softmax.
// e^{2(q+k)} = e^{2q} * e^{2k}: exponentiate projections once (proj kernel).
// 4 h-terms share one rcp: sum wv_i/t_i = num/(t0*t1*t2*t3).
//
// R4: grid-barrier fusion => cross-XCD coherence storm. Two launches.
// R6/R8/R10: >~45 live VGPRs anywhere (deep unroll, arrays held across
//   barriers) under the 1024-thr/8-wave cap => silent scratch spill storm
//   (WRITE_SIZE 27..904MB). Tripwire: WRITE_SIZE must stay ~2MB.
// R9: global_load_lds staging works (no spill); R10 fixed its bank conflicts
//   (6.29M -> 98K) via wave-uniform h-row + lane-contiguous k map.
// R11: R10 phase 1 + register-light phase 2 (writes attn transposed into
//   dead kst scratch, no reg carry across barriers) + V-reuse phase 3
//   (each V float4 loaded once, shared by 4 q; 16 acc, unroll<=2).

#define B_ 4
#define Q_ 512
#define K_ 512
#define H_ 256
#define QE_ELEMS (B_ * Q_ * H_)           // 524288
#define KE_ELEMS (B_ * H_ * K_)           // 524288

static constexpr float CEXP = 2.8853900817779268f; // 2*log2(e)
static constexpr float LOG2E = 1.4426950408889634f;

__device__ __forceinline__ float2 pk_fma(float2 a, float2 b, float2 c) {
    return make_float2(fmaf(a.x, b.x, c.x), fmaf(a.y, b.y, c.y));
}
__device__ __forceinline__ float2 pk_mul(float2 a, float2 b) {
    return make_float2(a.x * b.x, a.y * b.y);
}
__device__ __forceinline__ float2 bc2(float s) { return make_float2(s, s); }

// async global->LDS, 16B per lane (global_load_lds_dwordx4)
__device__ __forceinline__ void gl_lds16(const float* g, float* l) {
    __builtin_amdgcn_global_load_lds(
        (const __attribute__((address_space(1))) void*)g,
        (__attribute__((address_space(3))) void*)l, 16, 0, 0);
}

// ---------------------------------------------------------------------------
// proj_exp: 256 blocks x 1024 thr. Block = one 64x64 output tile; 4 teams of
// 256 thr each reduce a 64-d quarter (double-buffered LDS, reg prefetch);
// LDS combine -> exp2 -> store.  blocks [0,128): qe; [128,256): ke[b][h][k].
// ---------------------------------------------------------------------------
#define PJ_AS(team, buf, dd, row) smem[(((team)*2 + (buf)) * 16 + (dd)) * 68 + (row)]
#define PJ_SS(team, buf, dd, row) smem[8704 + (((team)*2 + (buf)) * 16 + (dd)) * 68 + (row)]

__global__ __launch_bounds__(1024, 4) void proj_exp(
    const float* __restrict__ queries, const float* __restrict__ keys,
    const float* __restrict__ Wq, const float* __restrict__ Wk,
    float* __restrict__ qe, float* __restrict__ ke)
{
    __shared__ __align__(16) float smem[17408];   // 69632 B

    const int bid = blockIdx.x;
    const int team = threadIdx.x >> 8;   // d-quarter 0..3 (64 d each)
    const int tid = threadIdx.x & 255;

    const float* A; const float* S; float* C; int ldc;
    if (bid < 128) {                 // qe: [B*Q=2048 x H=256], 32x4 tiles
        int mt = bid >> 2, nt = bid & 3;
        A = queries + (mt * 64) * H_;
        S = Wq + (nt * 64) * H_;
        C = qe + (mt * 64) * H_ + nt * 64;
        ldc = H_;
    } else {                         // ke: per-b [H=256 x K=512], 4x8 tiles
        int id = bid - 128;
        int b = id >> 5, mt = (id >> 3) & 3, nt = id & 7;
        A = Wk + (mt * 64) * H_;
        S = keys + ((long)(b * K_ + nt * 64)) * H_;
        C = ke + ((long)(b * H_ + mt * 64)) * K_ + nt * 64;
        ldc = K_;
    }

    const int tx = tid & 15;         // n0 = tx*4
    const int ty = tid >> 4;         // m0 = ty*4
    const int ldr = tid >> 2;        // staging row 0..63
    const int ldd = (tid & 3) * 4;   // staging d-offset 0,4,8,12
    const float* GA = A + ldr * H_ + team * 64 + ldd;
    const float* GS = S + ldr * H_ + team * 64 + ldd;

    float4 av = *(const float4*)GA;
    float4 sv = *(const float4*)GS;
    PJ_AS(team, 0, ldd + 0, ldr) = av.x; PJ_AS(team, 0, ldd + 1, ldr) = av.y;
    PJ_AS(team, 0, ldd + 2, ldr) = av.z; PJ_AS(team, 0, ldd + 3, ldr) = av.w;
    PJ_SS(team, 0, ldd + 0, ldr) = sv.x; PJ_SS(team, 0, ldd + 1, ldr) = sv.y;
    PJ_SS(team, 0, ldd + 2, ldr) = sv.z; PJ_SS(team, 0, ldd + 3, ldr) = sv.w;

    float acc[4][4] = {};
#pragma unroll
    for (int c = 0; c < 4; ++c) {    // 4 chunks x 16 d = 64 d per team
        const int cur = c & 1;
        if (c < 3) {                 // register prefetch of next chunk
            av = *(const float4*)(GA + (c + 1) * 16);
            sv = *(const float4*)(GS + (c + 1) * 16);
        }
        __syncthreads();             // buf[cur] writes visible
#pragma unroll
        for (int dd = 0; dd < 16; ++dd) {
            float4 a4 = *(const float4*)&PJ_AS(team, cur, dd, ty * 4);
            float4 b4 = *(const float4*)&PJ_SS(team, cur, dd, tx * 4);
            float am[4] = {a4.x, a4.y, a4.z, a4.w};
            float bn[4] = {b4.x, b4.y, b4.z, b4.w};
#pragma unroll
            for (int i = 0; i < 4; ++i)
#pragma unroll
                for (int j = 0; j < 4; ++j)
                    acc[i][j] = fmaf(am[i], bn[j], acc[i][j]);
        }
        if (c < 3) {                 // fill other buffer (last read 2 iters ago)
            const int nxt = cur ^ 1;
            PJ_AS(team, nxt, ldd + 0, ldr) = av.x;
            PJ_AS(team, nxt, ldd + 1, ldr) = av.y;
            PJ_AS(team, nxt, ldd + 2, ldr) = av.z;
            PJ_AS(team, nxt, ldd + 3, ldr) = av.w;
            PJ_SS(team, nxt, ldd + 0, ldr) = sv.x;
            PJ_SS(team, nxt, ldd + 1, ldr) = sv.y;
            PJ_SS(team, nxt, ldd + 2, ldr) = sv.z;
            PJ_SS(team, nxt, ldd + 3, ldr) = sv.w;
        }
    }

    // combine 4 d-quarter partials via LDS (reuse staging), exp, store
    __syncthreads();                 // all staging reads complete
    if (team > 0) {
        float* Cmb = smem + (team - 1) * 4352;   // 64 x 68 tile
#pragma unroll
        for (int i = 0; i < 4; ++i) {
            float4 o = {acc[i][0], acc[i][1], acc[i][2], acc[i][3]};
            *(float4*)&Cmb[(ty * 4 + i) * 68 + tx * 4] = o;
        }
    }
    __syncthreads();
    if (team == 0) {
#pragma unroll
        for (int i = 0; i < 4; ++i) {
            const int off = (ty * 4 + i) * 68 + tx * 4;
            float4 p1 = *(const float4*)&smem[off];
            float4 p2 = *(const float4*)&smem[4352 + off];
            float4 p3 = *(const float4*)&smem[8704 + off];
            float4 o;
            o.x = __builtin_amdgcn_exp2f(CEXP * (acc[i][0] + p1.x + p2.x + p3.x));
            o.y = __builtin_amdgcn_exp2f(CEXP * (acc[i][1] + p1.y + p2.y + p3.y));
            o.z = __builtin_amdgcn_exp2f(CEXP * (acc[i][2] + p1.z + p2.z + p3.z));
            o.w = __builtin_amdgcn_exp2f(CEXP * (acc[i][3] + p1.w + p2.w + p3.w));
            *(float4*)&C[(ty * 4 + i) * ldc + tx * 4] = o;
        }
    }
}

// ---------------------------------------------------------------------------
// attn: 512 blocks x 1024 thr. LDS 78848B -> 2 blocks/CU, VGPR<=64.
// XCD-affine: bid%8 -> XCD; XCD pair {2b,2b+1} serves batch b.
// Phase 1: ke via double-buffered global_load_lds chunks (16h x 512k);
//   wave-uniform h-quad + lane-contiguous k reads (conflict-free, R10).
// Phase 2: softmax (wave q<4 of first 4 waves), writes attn TRANSPOSED
//   into dead kst scratch kT[k][q] (no reg carry across barriers).
// Phase 3: thread = (h-quad, 32-k segment); each V float4 loaded once,
//   shared by all 4 q (16 fma / 16B); barrier; kst reduction.
// ---------------------------------------------------------------------------
__global__ __launch_bounds__(1024, 8) void attn(
    const float* __restrict__ qe, const float* __restrict__ ke,
    const float* __restrict__ values, const float* __restrict__ wv,
    float* __restrict__ out)
{
    const int bid = blockIdx.x;
    const int xcd = bid & 7;
    const int b = xcd >> 1;
    const int q0 = (((bid >> 3) << 1) | (xcd & 1)) * 4;
    const int t = threadIdx.x;
    const int lane = t & 63;
    const int w = t >> 6;                 // wave 0..15

    // LDS: kst[2][16*512] | sQ[4*256] | wvs[256] | sS[4*512]  (78848 B)
    __shared__ __align__(16) float smem[2 * 8192 + 1024 + 256 + 2048];
    float* kst = smem;                    // 2 x 8192 (staging, then scratch)
    float* sQ  = smem + 16384;            // [4][H_]
    float* wvs = smem + 17408;            // [H_]
    float* sS  = smem + 17664;            // [4][K_] row-major scores

    sQ[t] = qe[((long)(b * Q_ + q0 + (t >> 8))) * H_ + (t & 255)];
    if (t < H_) wvs[t] = wv[t];
    // first in-loop barrier covers sQ/wvs visibility

    // ---- Phase 1: scores, LDS-staged ke, conflict-free map
    {
        const float* keB = ke + (long)b * H_ * K_;
        const int sh = t >> 7;            // staging row 0..7
        const int sk = (t & 127) * 4;     // staging col (float4)
        const int hq4 = (w & 3) * 4;      // wave-uniform h-quad base
        const int kseg = w >> 2;          // 0..3
        const int k2 = kseg * 128 + lane * 2;

        gl_lds16(keB + (0 * 16 + sh) * K_ + sk, kst + t * 4);
        gl_lds16(keB + (0 * 16 + 8 + sh) * K_ + sk, kst + 4096 + t * 4);

        float2 acc[4] = {};               // acc[q]: .x k2, .y k2+1
        const float2 one2 = {1.0f, 1.0f};

        for (int c = 0; c < 16; ++c) {
            const int cur = c & 1;
            __syncthreads();              // drains stage(c); chunk c ready
            if (c < 15) {                 // async-fill other buffer NOW
                float* nb = kst + (cur ^ 1) * 8192;
                gl_lds16(keB + ((c + 1) * 16 + sh) * K_ + sk, nb + t * 4);
                gl_lds16(keB + ((c + 1) * 16 + 8 + sh) * K_ + sk,
                         nb + 4096 + t * 4);
            }
            const float* kb = kst + cur * 8192;
            float2 c0 = *(const float2*)&kb[(hq4 + 0) * 512 + k2];
            float2 c1 = *(const float2*)&kb[(hq4 + 1) * 512 + k2];
            float2 c2 = *(const float2*)&kb[(hq4 + 2) * 512 + k2];
            float2 c3 = *(const float2*)&kb[(hq4 + 3) * 512 + k2];
            const int h = c * 16 + hq4;
            float4 w4 = *(const float4*)&wvs[h];
#pragma unroll
            for (int q = 0; q < 4; ++q) {
                float4 e = *(const float4*)&sQ[q * H_ + h];
                float2 t0 = pk_fma(bc2(e.x), c0, one2);
                float2 t1 = pk_fma(bc2(e.y), c1, one2);
                float2 t2 = pk_fma(bc2(e.z), c2, one2);
                float2 t3 = pk_fma(bc2(e.w), c3, one2);
                float2 d01 = pk_mul(t0, t1);
                float2 d23 = pk_mul(t2, t3);
                float2 n01 = pk_fma(bc2(w4.x), t1, pk_mul(bc2(w4.y), t0));
                float2 n23 = pk_fma(bc2(w4.z), t3, pk_mul(bc2(w4.w), t2));
                float2 num = pk_fma(n01, d23, pk_mul(n23, d01));
                float2 den = pk_mul(d01, d23);
                acc[q].x = fmaf(num.x, __builtin_amdgcn_rcpf(den.x), acc[q].x);
                acc[q].y = fmaf(num.y, __builtin_amdgcn_rcpf(den.y), acc[q].y);
            }
        }

        __syncthreads();                  // chunk-15 reads done; kst reusable
        // cross-wave h-combine via scratch: part[(w*4+q)*64+lane] (float2)
#pragma unroll
        for (int q = 0; q < 4; ++q)
            *(float2*)&kst[((w * 4 + q) * 64 + lane) * 2] = acc[q];
        __syncthreads();
        {
            const int ks2 = t >> 8;       // 0..3
            const int q = (t >> 6) & 3;
            float2 s = {0.f, 0.f};
#pragma unroll
            for (int hq = 0; hq < 4; ++hq) {
                float2 p = *(const float2*)
                    &kst[(((ks2 * 4 + hq) * 4 + q) * 64 + lane) * 2];
                s.x += p.x; s.y += p.y;
            }
            float2 o = {-2.0f * s.x, -2.0f * s.y};
            *(float2*)&sS[q * K_ + ks2 * 128 + lane * 2] = o;
        }
    }
    __syncthreads();

    // ---- Phase 2: softmax, wave q<4 -> row q; writes TRANSPOSED kT[k][q]
    // into kst (dead after phase-1 combine). No register carry across syncs.
    if (t < 256) {
        const int q = t >> 6;
        float sv[8];
        float m = -INFINITY;
#pragma unroll
        for (int j = 0; j < 8; ++j) {
            sv[j] = sS[q * K_ + lane + 64 * j];
            m = fmaxf(m, sv[j]);
        }
#pragma unroll
        for (int off = 32; off >= 1; off >>= 1) m = fmaxf(m, __shfl_xor(m, off));
        float sum = 0.f;
#pragma unroll
        for (int j = 0; j < 8; ++j) {
            sv[j] = __builtin_amdgcn_exp2f((sv[j] - m) * LOG2E);
            sum += sv[j];
        }
#pragma unroll
        for (int off = 32; off >= 1; off >>= 1) sum += __shfl_xor(sum, off);
        float rs = 1.0f / sum;
#pragma unroll
        for (int j = 0; j < 8; ++j)
            kst[(lane + 64 * j) * 4 + q] = sv[j] * rs;   // kT[k][q]
    }
    __syncthreads();

    // ---- Phase 3: attn @ V; V loaded once, shared across 4 q.
    // thread = (h4 = lane*4, kseg = w -> 32 k). 16 acc VGPRs, unroll 2 max.
    {
        const int h4 = lane * 4;
        const float* vb = values + (long)b * K_ * H_ + h4;
        float4 a0 = {0,0,0,0}, a1 = {0,0,0,0}, a2 = {0,0,0,0}, a3 = {0,0,0,0};
        const int kbeg = w * 32;
#pragma unroll 2
        for (int k = kbeg; k < kbeg + 32; ++k) {
            float4 v = *(const float4*)&vb[(long)k * H_];
            float4 a = *(const float4*)&kst[k * 4];  // b128 broadcast
            a0.x = fmaf(a.x, v.x, a0.x); a0.y = fmaf(a.x, v.y, a0.y);
            a0.z = fmaf(a.x, v.z, a0.z); a0.w = fmaf(a.x, v.w, a0.w);
            a1.x = fmaf(a.y, v.x, a1.x); a1.y = fmaf(a.y, v.y, a1.y);
            a1.z = fmaf(a.y, v.z, a1.z); a1.w = fmaf(a.y, v.w, a1.w);
            a2.x = fmaf(a.z, v.x, a2.x); a2.y = fmaf(a.z, v.y, a2.y);
            a2.z = fmaf(a.z, v.z, a2.z); a2.w = fmaf(a.z, v.w, a2.w);
            a3.x = fmaf(a.w, v.x, a3.x); a3.y = fmaf(a.w, v.y, a3.y);
            a3.z = fmaf(a.w, v.z, a3.z); a3.w = fmaf(a.w, v.w, a3.w);
        }
        __syncthreads();                  // kT reads done before kst reuse
        float4* sRed = (float4*)kst;      // 16 kseg x 4 q x 64 lanes = 64KB
        sRed[(w * 4 + 0) * 64 + lane] = a0;
        sRed[(w * 4 + 1) * 64 + lane] = a1;
        sRed[(w * 4 + 2) * 64 + lane] = a2;
        sRed[(w * 4 + 3) * 64 + lane] = a3;
        __syncthreads();
        if (t < 256) {
            const int q = t >> 6;
            float4 s = {0.f, 0.f, 0.f, 0.f};
#pragma unroll
            for (int kk = 0; kk < 16; ++kk) {
                float4 p = sRed[(kk * 4 + q) * 64 + lane];
                s.x += p.x; s.y += p.y; s.z += p.z; s.w += p.w;
            }
            *(float4*)&out[((long)(b * Q_ + q0 + q)) * H_ + lane * 4] = s;
        }
    }
}

extern "C" void kernel_launch(void* const* d_in, const int* in_sizes, int n_in,
                              void* d_out, int out_size, void* d_ws, size_t ws_size,
                              hipStream_t stream) {
    const float* queries = (const float*)d_in[0];  // [B,Q,H]
    const float* keys    = (const float*)d_in[1];  // [B,K,H]
    const float* values  = (const float*)d_in[2];  // [B,K,H]
    const float* Wq      = (const float*)d_in[3];  // [H,H]
    const float* Wk      = (const float*)d_in[4];  // [H,H]
    const float* wv      = (const float*)d_in[5];  // [H]
    float* out = (float*)d_out;

    // ws: [qe 2MB][ke 2MB]
    float* qe = (float*)d_ws;
    float* ke = qe + QE_ELEMS;

    proj_exp<<<256, 1024, 0, stream>>>(queries, keys, Wq, Wk, qe, ke);
    attn<<<512, 1024, 0, stream>>>(qe, ke, values, wv, out);
}

// Round 12
// 136.895 us; speedup vs baseline: 3.9405x; 3.8860x over previous
//
#include <hip/hip_runtime.h>
#include <hip/hip_bf16.h>
#include <math.h>

// AdditiveAttention: B=4, Q=512, K=512, H=256, fp32.
// scores[b,q,k] = sum_h wv_h * tanh(qp + kp) -> softmax_k -> @V
// tanh(x) = 1 - 2/(1+e^{2x}); sum_h wv_h drops out of softmax.
// e^{2(q+k)} = e^{2q} * e^{2k}: exponentiate projections once (proj kernel).
// 4 h-terms share one rcp: sum wv_i/t_i = num/(t0*t1*t2*t3).
//
// R4: grid-barrier fusion => cross-XCD coherence storm. Two launches.
// R6/R8: deep register pipelines => scratch spill storm.
// R9: global_load_lds staging clean (FETCH 5MB) WITH "#pragma unroll 2";
//     bank conflicts 6.29M from per-lane-h read map.
// R10/R11: conflict-free map (98K) but dropped the unroll pragma -> LLVM
//     full-unrolls the 16-iter staging loop -> hoist -> ~1.5GB scratch storm
//     (theory under test this round).
// R12: R10 phase-1 map + "#pragma unroll 2" restored; phases 2/3 are the
//     R7/R9 proven forms. Tripwire: WRITE_SIZE must be ~2MB.

#define B_ 4
#define Q_ 512
#define K_ 512
#define H_ 256
#define QE_ELEMS (B_ * Q_ * H_)           // 524288
#define KE_ELEMS (B_ * H_ * K_)           // 524288

static constexpr float CEXP = 2.8853900817779268f; // 2*log2(e)
static constexpr float LOG2E = 1.4426950408889634f;

__device__ __forceinline__ float2 pk_fma(float2 a, float2 b, float2 c) {
    return make_float2(fmaf(a.x, b.x, c.x), fmaf(a.y, b.y, c.y));
}
__device__ __forceinline__ float2 pk_mul(float2 a, float2 b) {
    return make_float2(a.x * b.x, a.y * b.y);
}
__device__ __forceinline__ float2 bc2(float s) { return make_float2(s, s); }

// async global->LDS, 16B per lane (global_load_lds_dwordx4)
__device__ __forceinline__ void gl_lds16(const float* g, float* l) {
    __builtin_amdgcn_global_load_lds(
        (const __attribute__((address_space(1))) void*)g,
        (__attribute__((address_space(3))) void*)l, 16, 0, 0);
}

// ---------------------------------------------------------------------------
// proj_exp: 256 blocks x 1024 thr. Block = one 64x64 output tile; 4 teams of
// 256 thr each reduce a 64-d quarter (double-buffered LDS, reg prefetch);
// LDS combine -> exp2 -> store.  blocks [0,128): qe; [128,256): ke[b][h][k].
// ---------------------------------------------------------------------------
#define PJ_AS(team, buf, dd, row) smem[(((team)*2 + (buf)) * 16 + (dd)) * 68 + (row)]
#define PJ_SS(team, buf, dd, row) smem[8704 + (((team)*2 + (buf)) * 16 + (dd)) * 68 + (row)]

__global__ __launch_bounds__(1024, 4) void proj_exp(
    const float* __restrict__ queries, const float* __restrict__ keys,
    const float* __restrict__ Wq, const float* __restrict__ Wk,
    float* __restrict__ qe, float* __restrict__ ke)
{
    __shared__ __align__(16) float smem[17408];   // 69632 B

    const int bid = blockIdx.x;
    const int team = threadIdx.x >> 8;   // d-quarter 0..3 (64 d each)
    const int tid = threadIdx.x & 255;

    const float* A; const float* S; float* C; int ldc;
    if (bid < 128) {                 // qe: [B*Q=2048 x H=256], 32x4 tiles
        int mt = bid >> 2, nt = bid & 3;
        A = queries + (mt * 64) * H_;
        S = Wq + (nt * 64) * H_;
        C = qe + (mt * 64) * H_ + nt * 64;
        ldc = H_;
    } else {                         // ke: per-b [H=256 x K=512], 4x8 tiles
        int id = bid - 128;
        int b = id >> 5, mt = (id >> 3) & 3, nt = id & 7;
        A = Wk + (mt * 64) * H_;
        S = keys + ((long)(b * K_ + nt * 64)) * H_;
        C = ke + ((long)(b * H_ + mt * 64)) * K_ + nt * 64;
        ldc = K_;
    }

    const int tx = tid & 15;         // n0 = tx*4
    const int ty = tid >> 4;         // m0 = ty*4
    const int ldr = tid >> 2;        // staging row 0..63
    const int ldd = (tid & 3) * 4;   // staging d-offset 0,4,8,12
    const float* GA = A + ldr * H_ + team * 64 + ldd;
    const float* GS = S + ldr * H_ + team * 64 + ldd;

    float4 av = *(const float4*)GA;
    float4 sv = *(const float4*)GS;
    PJ_AS(team, 0, ldd + 0, ldr) = av.x; PJ_AS(team, 0, ldd + 1, ldr) = av.y;
    PJ_AS(team, 0, ldd + 2, ldr) = av.z; PJ_AS(team, 0, ldd + 3, ldr) = av.w;
    PJ_SS(team, 0, ldd + 0, ldr) = sv.x; PJ_SS(team, 0, ldd + 1, ldr) = sv.y;
    PJ_SS(team, 0, ldd + 2, ldr) = sv.z; PJ_SS(team, 0, ldd + 3, ldr) = sv.w;

    float acc[4][4] = {};
#pragma unroll
    for (int c = 0; c < 4; ++c) {    // 4 chunks x 16 d = 64 d per team
        const int cur = c & 1;
        if (c < 3) {                 // register prefetch of next chunk
            av = *(const float4*)(GA + (c + 1) * 16);
            sv = *(const float4*)(GS + (c + 1) * 16);
        }
        __syncthreads();             // buf[cur] writes visible
#pragma unroll
        for (int dd = 0; dd < 16; ++dd) {
            float4 a4 = *(const float4*)&PJ_AS(team, cur, dd, ty * 4);
            float4 b4 = *(const float4*)&PJ_SS(team, cur, dd, tx * 4);
            float am[4] = {a4.x, a4.y, a4.z, a4.w};
            float bn[4] = {b4.x, b4.y, b4.z, b4.w};
#pragma unroll
            for (int i = 0; i < 4; ++i)
#pragma unroll
                for (int j = 0; j < 4; ++j)
                    acc[i][j] = fmaf(am[i], bn[j], acc[i][j]);
        }
        if (c < 3) {                 // fill other buffer (last read 2 iters ago)
            const int nxt = cur ^ 1;
            PJ_AS(team, nxt, ldd + 0, ldr) = av.x;
            PJ_AS(team, nxt, ldd + 1, ldr) = av.y;
            PJ_AS(team, nxt, ldd + 2, ldr) = av.z;
            PJ_AS(team, nxt, ldd + 3, ldr) = av.w;
            PJ_SS(team, nxt, ldd + 0, ldr) = sv.x;
            PJ_SS(team, nxt, ldd + 1, ldr) = sv.y;
            PJ_SS(team, nxt, ldd + 2, ldr) = sv.z;
            PJ_SS(team, nxt, ldd + 3, ldr) = sv.w;
        }
    }

    // combine 4 d-quarter partials via LDS (reuse staging), exp, store
    __syncthreads();                 // all staging reads complete
    if (team > 0) {
        float* Cmb = smem + (team - 1) * 4352;   // 64 x 68 tile
#pragma unroll
        for (int i = 0; i < 4; ++i) {
            float4 o = {acc[i][0], acc[i][1], acc[i][2], acc[i][3]};
            *(float4*)&Cmb[(ty * 4 + i) * 68 + tx * 4] = o;
        }
    }
    __syncthreads();
    if (team == 0) {
#pragma unroll
        for (int i = 0; i < 4; ++i) {
            const int off = (ty * 4 + i) * 68 + tx * 4;
            float4 p1 = *(const float4*)&smem[off];
            float4 p2 = *(const float4*)&smem[4352 + off];
            float4 p3 = *(const float4*)&smem[8704 + off];
            float4 o;
            o.x = __builtin_amdgcn_exp2f(CEXP * (acc[i][0] + p1.x + p2.x + p3.x));
            o.y = __builtin_amdgcn_exp2f(CEXP * (acc[i][1] + p1.y + p2.y + p3.y));
            o.z = __builtin_amdgcn_exp2f(CEXP * (acc[i][2] + p1.z + p2.z + p3.z));
            o.w = __builtin_amdgcn_exp2f(CEXP * (acc[i][3] + p1.w + p2.w + p3.w));
            *(float4*)&C[(ty * 4 + i) * ldc + tx * 4] = o;
        }
    }
}

// ---------------------------------------------------------------------------
// attn: 512 blocks x 1024 thr. LDS 78848B -> 2 blocks/CU.
// XCD-affine: bid%8 -> XCD; XCD pair {2b,2b+1} serves batch b.
// Phase 1: ke via double-buffered global_load_lds chunks (16h x 512k),
//   "#pragma unroll 2" on the chunk loop (R9-proven codegen; full unroll
//   spills). Wave-uniform h-quad + lane-contiguous k reads (conflict-free).
//   Cross-wave h-combine via kst scratch.
// Phase 2: softmax in-place on sS, wave q<4 (R7-proven form).
// Phase 3: thread = (h-quad, q, k-quarter), R7-proven form; sRed in kst.
// ---------------------------------------------------------------------------
__global__ __launch_bounds__(1024, 8) void attn(
    const float* __restrict__ qe, const float* __restrict__ ke,
    const float* __restrict__ values, const float* __restrict__ wv,
    float* __restrict__ out)
{
    const int bid = blockIdx.x;
    const int xcd = bid & 7;
    const int b = xcd >> 1;
    const int q0 = (((bid >> 3) << 1) | (xcd & 1)) * 4;
    const int t = threadIdx.x;
    const int lane = t & 63;
    const int w = t >> 6;                 // wave 0..15

    // LDS: kst[2][8192] | sQ[4*256] | wvs[256] | sS[4*512]  (78848 B)
    __shared__ __align__(16) float smem[16384 + 1024 + 256 + 2048];
    float* kst = smem;                    // staging, then scratch/sRed
    float* sQ  = smem + 16384;            // [4][H_]
    float* wvs = smem + 17408;            // [H_]
    float* sS  = smem + 17664;            // [4][K_]

    sQ[t] = qe[((long)(b * Q_ + q0 + (t >> 8))) * H_ + (t & 255)];
    if (t < H_) wvs[t] = wv[t];
    // first in-loop barrier covers sQ/wvs visibility

    // ---- Phase 1: scores, LDS-staged ke, conflict-free map
    {
        const float* keB = ke + (long)b * H_ * K_;
        const int sh = t >> 7;            // staging row 0..7
        const int sk = (t & 127) * 4;     // staging col (float4)
        const int hq4 = (w & 3) * 4;      // wave-uniform h-quad base
        const int kseg = w >> 2;          // 0..3
        const int k2 = kseg * 128 + lane * 2;

        gl_lds16(keB + sh * K_ + sk, kst + t * 4);
        gl_lds16(keB + (8 + sh) * K_ + sk, kst + 4096 + t * 4);

        float2 acc[4] = {};               // acc[q]: .x k2, .y k2+1
        const float2 one2 = {1.0f, 1.0f};

#pragma unroll 2
        for (int c = 0; c < 16; ++c) {    // KEEP unroll 2: full unroll spills
            const int cur = c & 1;
            __syncthreads();              // drains stage(c); chunk c ready
            if (c < 15) {                 // async-fill other buffer NOW
                float* nb = kst + (cur ^ 1) * 8192;
                gl_lds16(keB + ((c + 1) * 16 + sh) * K_ + sk, nb + t * 4);
                gl_lds16(keB + ((c + 1) * 16 + 8 + sh) * K_ + sk,
                         nb + 4096 + t * 4);
            }
            const float* kb = kst + cur * 8192;
            float2 c0 = *(const float2*)&kb[(hq4 + 0) * 512 + k2];
            float2 c1 = *(const float2*)&kb[(hq4 + 1) * 512 + k2];
            float2 c2 = *(const float2*)&kb[(hq4 + 2) * 512 + k2];
            float2 c3 = *(const float2*)&kb[(hq4 + 3) * 512 + k2];
            const int h = c * 16 + hq4;
            float4 w4 = *(const float4*)&wvs[h];
#pragma unroll
            for (int q = 0; q < 4; ++q) {
                float4 e = *(const float4*)&sQ[q * H_ + h];
                float2 t0 = pk_fma(bc2(e.x), c0, one2);
                float2 t1 = pk_fma(bc2(e.y), c1, one2);
                float2 t2 = pk_fma(bc2(e.z), c2, one2);
                float2 t3 = pk_fma(bc2(e.w), c3, one2);
                float2 d01 = pk_mul(t0, t1);
                float2 d23 = pk_mul(t2, t3);
                float2 n01 = pk_fma(bc2(w4.x), t1, pk_mul(bc2(w4.y), t0));
                float2 n23 = pk_fma(bc2(w4.z), t3, pk_mul(bc2(w4.w), t2));
                float2 num = pk_fma(n01, d23, pk_mul(n23, d01));
                float2 den = pk_mul(d01, d23);
                acc[q].x = fmaf(num.x, __builtin_amdgcn_rcpf(den.x), acc[q].x);
                acc[q].y = fmaf(num.y, __builtin_amdgcn_rcpf(den.y), acc[q].y);
            }
        }

        __syncthreads();                  // chunk-15 reads done; kst reusable
        // cross-wave h-combine via kst scratch: part[(w*4+q)*64+lane] float2
#pragma unroll
        for (int q = 0; q < 4; ++q)
            *(float2*)&kst[((w * 4 + q) * 64 + lane) * 2] = acc[q];
        __syncthreads();
        {
            const int ks2 = t >> 8;       // 0..3
            const int q = (t >> 6) & 3;
            float2 s = {0.f, 0.f};
#pragma unroll
            for (int hq = 0; hq < 4; ++hq) {
                float2 p = *(const float2*)
                    &kst[(((ks2 * 4 + hq) * 4 + q) * 64 + lane) * 2];
                s.x += p.x; s.y += p.y;
            }
            float2 o = {-2.0f * s.x, -2.0f * s.y};
            *(float2*)&sS[q * K_ + ks2 * 128 + lane * 2] = o;
        }
    }
    __syncthreads();

    // ---- Phase 2: softmax, wave q<4 -> row q, in-place on sS (R7 form)
    if (t < 256) {
        const int q = t >> 6;
        float sv[8];
        float m = -INFINITY;
#pragma unroll
        for (int j = 0; j < 8; ++j) {
            sv[j] = sS[q * K_ + lane + 64 * j];
            m = fmaxf(m, sv[j]);
        }
#pragma unroll
        for (int off = 32; off >= 1; off >>= 1) m = fmaxf(m, __shfl_xor(m, off));
        float sum = 0.f;
#pragma unroll
        for (int j = 0; j < 8; ++j) {
            sv[j] = __builtin_amdgcn_exp2f((sv[j] - m) * LOG2E);
            sum += sv[j];
        }
#pragma unroll
        for (int off = 32; off >= 1; off >>= 1) sum += __shfl_xor(sum, off);
        float rs = 1.0f / sum;
#pragma unroll
        for (int j = 0; j < 8; ++j) sS[q * K_ + lane + 64 * j] = sv[j] * rs;
    }
    __syncthreads();

    // ---- Phase 3: attn @ V (R7 form). thread = (h4, q, k-quarter).
    // sRed lives in kst (dead since phase-1 combine) -> no alias with sS.
    {
        const int h4 = lane * 4;
        const int q = (t >> 6) & 3;
        const int kq = t >> 8;
        const float* vb = values + (long)b * K_ * H_ + h4;
        const float* sSq = sS + q * K_;
        float4 acc = {0.f, 0.f, 0.f, 0.f};
        const int kbeg = kq * 128;
#pragma unroll 2
        for (int k = kbeg; k < kbeg + 128; k += 4) {
            float4 a = *(const float4*)&sSq[k];
            float4 v0 = *(const float4*)&vb[(k + 0) * H_];
            float4 v1 = *(const float4*)&vb[(k + 1) * H_];
            float4 v2 = *(const float4*)&vb[(k + 2) * H_];
            float4 v3 = *(const float4*)&vb[(k + 3) * H_];
            acc.x = fmaf(a.x, v0.x, fmaf(a.y, v1.x, fmaf(a.z, v2.x, fmaf(a.w, v3.x, acc.x))));
            acc.y = fmaf(a.x, v0.y, fmaf(a.y, v1.y, fmaf(a.z, v2.y, fmaf(a.w, v3.y, acc.y))));
            acc.z = fmaf(a.x, v0.z, fmaf(a.y, v1.z, fmaf(a.z, v2.z, fmaf(a.w, v3.z, acc.z))));
            acc.w = fmaf(a.x, v0.w, fmaf(a.y, v1.w, fmaf(a.z, v2.w, fmaf(a.w, v3.w, acc.w))));
        }
        float4* sRed = (float4*)kst;      // 768 float4 = 12KB, fits in kst
        if (kq) sRed[(kq - 1) * 256 + q * 64 + lane] = acc;
        __syncthreads();
        if (kq == 0) {
            float4 p1 = sRed[q * 64 + lane];
            float4 p2 = sRed[256 + q * 64 + lane];
            float4 p3 = sRed[512 + q * 64 + lane];
            acc.x += p1.x + p2.x + p3.x;
            acc.y += p1.y + p2.y + p3.y;
            acc.z += p1.z + p2.z + p3.z;
            acc.w += p1.w + p2.w + p3.w;
            *(float4*)&out[((long)(b * Q_ + q0 + q)) * H_ + h4] = acc;
        }
    }
}

extern "C" void kernel_launch(void* const* d_in, const int* in_sizes, int n_in,
                              void* d_out, int out_size, void* d_ws, size_t ws_size,
                              hipStream_t stream) {
    const float* queries = (const float*)d_in[0];  // [B,Q,H]
    const float* keys    = (const float*)d_in[1];  // [B,K,H]
    const float* values  = (const float*)d_in[2];  // [B,K,H]
    const float* Wq      = (const float*)d_in[3];  // [H,H]
    const float* Wk      = (const float*)d_in[4];  // [H,H]
    const float* wv      = (const float*)d_in[5];  // [H]
    float* out = (float*)d_out;

    // ws: [qe 2MB][ke 2MB]
    float* qe = (float*)d_ws;
    float* ke = qe + QE_ELEMS;

    proj_exp<<<256, 1024, 0, stream>>>(queries, keys, Wq, Wk, qe, ke);
    attn<<<512, 1024, 0, stream>>>(qe, ke, values, wv, out);
}